// Round 13
// baseline (258.241 us; speedup 1.0000x reference)
//
#include <hip/hip_runtime.h>
#include <hip/hip_bf16.h>
#include <math.h>

#define HH 512
#define NVARS 16384
#define NPOS 4096
#define NMS 4096
#define NEGV -1.0e30f
#define RSQRT_H 0.04419417382415922f   // 1/sqrt(512)

typedef unsigned short u16;
typedef unsigned char u8;
typedef __attribute__((ext_vector_type(8))) short bf16x8;
typedef __attribute__((ext_vector_type(4))) float f32x4;

struct SPart { float m; float s; int a; int pad; };

__device__ inline u16 f2bf(float f) {
  unsigned u = __float_as_uint(f);
  unsigned r = (u + 0x7fffu + ((u >> 16) & 1u)) >> 16;
  return (u16)r;
}
__device__ inline float bf2f(u16 h) { return __uint_as_float(((unsigned)h) << 16); }

__device__ inline void wreduce_maxidx(float& v, int& idx) {
#pragma unroll
  for (int m = 1; m < 64; m <<= 1) {
    float ov = __shfl_xor(v, m, 64);
    int oi = __shfl_xor(idx, m, 64);
    if (ov > v || (ov == v && oi < idx)) { v = ov; idx = oi; }
  }
}

__device__ inline float wreduce_sum(float v) {
#pragma unroll
  for (int m = 1; m < 64; m <<= 1) v += __shfl_xor(v, m, 64);
  return v;
}

// async global->LDS: 64 lanes x 16 B contiguous; dst wave-uniform.
__device__ __forceinline__ void stage_frag(const u16* src, u16* dst) {
  __builtin_amdgcn_global_load_lds(
      (const __attribute__((address_space(1))) void*)src,
      (__attribute__((address_space(3))) void*)dst, 16, 0, 0);
}

// row-major f32 [.. x 512] -> fragment-major bf16 hi/lo for one frag.
__device__ __forceinline__ void do_tofrag(
    const float* __restrict__ src, u16* __restrict__ hi, u16* __restrict__ lo,
    int frag, int lane) {
  const int R = frag >> 4, K = frag & 15;
  const float* p = src + (size_t)(R * 16 + (lane & 15)) * HH + K * 32 + (lane >> 4) * 8;
  float v[8];
  *(float4*)&v[0] = *(const float4*)p;
  *(float4*)&v[4] = *(const float4*)(p + 4);
  u16 h[8], l[8];
#pragma unroll
  for (int e = 0; e < 8; ++e) { h[e] = f2bf(v[e]); l[e] = f2bf(v[e] - bf2f(h[e])); }
  size_t base = (size_t)frag * 512 + (size_t)lane * 8;
  *(ushort4*)(hi + base) = *(ushort4*)&h[0];
  *(ushort4*)(hi + base + 4) = *(ushort4*)&h[4];
  *(ushort4*)(lo + base) = *(ushort4*)&l[0];
  *(ushort4*)(lo + base + 4) = *(ushort4*)&l[4];
}

// ---------------------------------------------------------------------------
// MFMA macros: pass-outer interleave; pass order hh, hl, lh preserved.
#define MFMA16(A, B)                                                                 \
  _Pragma("unroll") for (int i_ = 0; i_ < 4; ++i_)                                   \
  _Pragma("unroll") for (int j_ = 0; j_ < 4; ++j_)                                   \
    acc[i_][j_] = __builtin_amdgcn_mfma_f32_16x16x32_bf16(A[i_], B[j_], acc[i_][j_], 0, 0, 0);

#define MFMAS(AH, AL, BH, BL)                                                        \
  do { MFMA16(AH, BH) MFMA16(AH, BL) MFMA16(AL, BH) } while (0)

#define LOADF(s, AH, AL, BH, BL, PAH, PAL, PBH, PBL)                                 \
  do {                                                                               \
    _Pragma("unroll") for (int f_ = 0; f_ < 4; ++f_) {                               \
      size_t oa_ = abase + (size_t)f_ * 8192 + (size_t)(s) * 512;                    \
      size_t ob_ = bbase + (size_t)f_ * 8192 + (size_t)(s) * 512;                    \
      AH[f_] = *(const bf16x8*)(PAH + oa_);                                          \
      AL[f_] = *(const bf16x8*)(PAL + oa_);                                          \
      BH[f_] = *(const bf16x8*)(PBH + ob_);                                          \
      BL[f_] = *(const bf16x8*)(PBL + ob_);                                          \
    }                                                                                \
  } while (0)

// ---------------------------------------------------------------------------
// weight tofrags: 3 matrices x 128 blocks
__global__ __launch_bounds__(256) void wtofrag_kernel(
    const float* __restrict__ varKw, u16* __restrict__ wkhi, u16* __restrict__ wklo,
    const float* __restrict__ WQw, u16* __restrict__ pwqhi, u16* __restrict__ pwqlo,
    const float* __restrict__ WKw, u16* __restrict__ pwkhi, u16* __restrict__ pwklo) {
  const int wb = blockIdx.x;
  const int m = wb >> 7;
  const int frag = (wb & 127) * 4 + (threadIdx.x >> 6);
  const float* src = (m == 0) ? varKw : (m == 1) ? WQw : WKw;
  u16* hi = (m == 0) ? wkhi : (m == 1) ? pwqhi : pwkhi;
  u16* lo = (m == 0) ? wklo : (m == 1) ? pwqlo : pwklo;
  do_tofrag(src, hi, lo, frag, threadIdx.x & 63);
}

// ---------------------------------------------------------------------------
// q/k projection: A = W fragments, B = gathered clause rows (on-the-fly
// split); direct fragment-store epilogue.
__global__ __launch_bounds__(256, 3) void proj_kernel(
    const float* __restrict__ clause,
    const int* __restrict__ pos_idx, const int* __restrict__ neg_idx,
    const u16* __restrict__ pwqhi, const u16* __restrict__ pwqlo,
    const u16* __restrict__ pwkhi, const u16* __restrict__ pwklo,
    const float* __restrict__ bQ, const float* __restrict__ bK,
    u16* __restrict__ qhi, u16* __restrict__ qlo,
    u16* __restrict__ khi, u16* __restrict__ klo) {
  const int* __restrict__ idx = blockIdx.z ? neg_idx : pos_idx;
  const u16* __restrict__ whp = blockIdx.z ? pwkhi : pwqhi;
  const u16* __restrict__ wlp = blockIdx.z ? pwklo : pwqlo;
  const float* __restrict__ bias = blockIdx.z ? bK : bQ;
  u16* __restrict__ ohi = blockIdx.z ? khi : qhi;
  u16* __restrict__ olo = blockIdx.z ? klo : qlo;

  const int t = threadIdx.x, lane = t & 63, wid = t >> 6;
  const int wn = wid & 1, wm = wid >> 1;
  const int row0 = blockIdx.x * 128;
  const int col0 = blockIdx.y * 128;

  const float* bptr[4];
#pragma unroll
  for (int j = 0; j < 4; ++j) {
    int g = idx[row0 + wn * 64 + j * 16 + (lane & 15)];
    bptr[j] = clause + (size_t)g * HH + (lane >> 4) * 8;
  }
  const size_t abase = (size_t)((col0 >> 4) + wm * 4) * 8192 + (size_t)lane * 8;

  f32x4 acc[4][4] = {};
#pragma unroll
  for (int s = 0; s < 16; ++s) {
    float rB[4][8];
    bf16x8 aH[4], aL[4], bH[4], bL[4];
#pragma unroll
    for (int f = 0; f < 4; ++f) {
      *(float4*)&rB[f][0] = *(const float4*)(bptr[f] + s * 32);
      *(float4*)&rB[f][4] = *(const float4*)(bptr[f] + s * 32 + 4);
      size_t oa = abase + (size_t)f * 8192 + (size_t)s * 512;
      aH[f] = *(const bf16x8*)(whp + oa);
      aL[f] = *(const bf16x8*)(wlp + oa);
    }
#pragma unroll
    for (int f = 0; f < 4; ++f)
#pragma unroll
      for (int e = 0; e < 8; ++e) {
        float v = rB[f][e];
        u16 h = f2bf(v);
        bH[f][e] = (short)h;
        bL[f][e] = (short)f2bf(v - bf2f(h));
      }
    MFMA16(aH, bH)
    MFMA16(aL, bH)
    MFMA16(aH, bL)
  }

  const int q4 = lane >> 4;
#pragma unroll
  for (int i = 0; i < 4; ++i) {
    const int hbase = col0 + wm * 64 + i * 16 + q4 * 4;
    float b0 = bias[hbase + 0], b1 = bias[hbase + 1];
    float b2 = bias[hbase + 2], b3 = bias[hbase + 3];
    const int lane16 = (lane & 15) + ((i & 1) * 2 + (q4 >> 1)) * 16;
    const int sub = (q4 & 1) * 4;
#pragma unroll
    for (int j = 0; j < 4; ++j) {
      const int frag = ((row0 + wn * 64 + j * 16) >> 4) * 16 +
                       ((col0 + wm * 64 + i * 16) >> 5);
      size_t base = (size_t)frag * 512 + (size_t)lane16 * 8 + sub;
      ushort4 hv, lv;
      float v;
      v = acc[i][j][0] + b0; hv.x = f2bf(v); lv.x = f2bf(v - bf2f(hv.x));
      v = acc[i][j][1] + b1; hv.y = f2bf(v); lv.y = f2bf(v - bf2f(hv.y));
      v = acc[i][j][2] + b2; hv.z = f2bf(v); lv.z = f2bf(v - bf2f(hv.z));
      v = acc[i][j][3] + b3; hv.w = f2bf(v); lv.w = f2bf(v - bf2f(hv.w));
      *(ushort4*)(ohi + base) = hv;
      *(ushort4*)(olo + base) = lv;
    }
  }
}

// ---------------------------------------------------------------------------
// MEGA kernel (LDS-light, co-schedulable): ids [0,1024) -> scores (reg-direct
// MFMA, builds its own mask words from keep/taken — the 32x32 block grid
// tiles the mask exactly once, so pack is absorbed for free); ids
// [1024,3072) -> qsum; ids [3072,7168) -> lit tofrag.
__global__ __launch_bounds__(256, 3) void mega_kernel(
    const u16* __restrict__ qhi, const u16* __restrict__ qlo,
    const u16* __restrict__ khi, const u16* __restrict__ klo,
    const void* __restrict__ keep, const void* __restrict__ taken,
    SPart* __restrict__ parts,
    const float* __restrict__ clause, double* __restrict__ qpart,
    const float* __restrict__ lit, u16* __restrict__ lithi, u16* __restrict__ litlo) {
  __shared__ unsigned long long mrow[128][2];
  __shared__ float s_rv[4]; __shared__ int s_ri[4]; __shared__ float s_rs[4];
  __shared__ float s_bm; __shared__ int s_ba;

  const int id = blockIdx.x;
  const int t = threadIdx.x;
  const int lane = t & 63;
  const int wid = t >> 6;

  if (id >= 3072) {
    // ---- lit tofrag ----
    const int frag = (id - 3072) * 4 + wid;
    do_tofrag(lit, lithi, litlo, frag, lane);
    return;
  }
  if (id >= 1024) {
    // ---- qsum: 32 rows/block, 16 float4 loads batched ----
    const int qb = id - 1024;               // [0,2048)
    const int fg = t & 127;
    const int rh = t >> 7;
    const float* base = clause + ((size_t)qb * 32 + rh * 16) * HH + fg * 4;
    float4 v[16];
#pragma unroll
    for (int u = 0; u < 16; ++u)
      v[u] = *(const float4*)(base + (size_t)u * HH);
    double a0 = 0.0, a1 = 0.0, a2 = 0.0, a3 = 0.0;
#pragma unroll
    for (int u = 0; u < 16; ++u) {
      a0 += (double)v[u].x; a1 += (double)v[u].y;
      a2 += (double)v[u].z; a3 += (double)v[u].w;
    }
    double* o = qpart + (size_t)(qb * 2 + rh) * HH + fg * 4;
    o[0] = a0; o[1] = a1; o[2] = a2; o[3] = a3;
    return;
  }

  // ---- scores (ids [0,1024)): register-direct 3-pass split MFMA ----
  const int wn = wid & 1, wm = wid >> 1;

  // XCD supertile swizzle (bijective on [0,1024))
  const int bid = id;
  const int xcd = bid & 7, p = bid >> 3;
  const int sp = p >> 6, q = p & 63;
  const int g = xcd * 2 + sp;
  const int bx = (g & 3) * 8 + (q & 7);
  const int by = (g >> 2) * 8 + (q >> 3);

  const int n0 = by * 128;
  const int m0 = bx * 128;

  // build mask words directly: thread t covers row t>>1, col-half t&1
  {
    const int r = t >> 1, half = t & 1;
    const unsigned* kw = (const unsigned*)keep;
    int f = 1;
#pragma unroll
    for (int i = 0; i < 16; ++i) f &= (kw[i] <= 1u);
    unsigned long long w = 0;
    if (!f) {
      // bool-byte masks: 64 bytes per thread
      const u8* kp = (const u8*)keep + (size_t)(n0 + r) * NMS + m0 + half * 64;
      const u8* tp = (const u8*)taken + (size_t)(n0 + r) * NMS + m0 + half * 64;
#pragma unroll
      for (int c = 0; c < 4; ++c) {
        uint4 kv = *(const uint4*)(kp + c * 16);
        uint4 tv = *(const uint4*)(tp + c * 16);
        unsigned kws[4] = {kv.x, kv.y, kv.z, kv.w};
        unsigned tws[4] = {tv.x, tv.y, tv.z, tv.w};
#pragma unroll
        for (int wi = 0; wi < 4; ++wi)
#pragma unroll
          for (int y = 0; y < 4; ++y) {
            unsigned kb = (kws[wi] >> (8 * y)) & 0xffu;
            unsigned tb = (tws[wi] >> (8 * y)) & 0xffu;
            w |= (unsigned long long)(kb && !tb) << (c * 16 + wi * 4 + y);
          }
      }
    } else {
      // int32 masks: 64 ints per thread
      const unsigned* kp = (const unsigned*)keep + (size_t)(n0 + r) * NMS + m0 + half * 64;
      const unsigned* tp = (const unsigned*)taken + (size_t)(n0 + r) * NMS + m0 + half * 64;
#pragma unroll
      for (int c = 0; c < 16; ++c) {
        uint4 kv = *(const uint4*)(kp + c * 4);
        uint4 tv = *(const uint4*)(tp + c * 4);
        w |= (unsigned long long)(kv.x && !tv.x) << (c * 4 + 0);
        w |= (unsigned long long)(kv.y && !tv.y) << (c * 4 + 1);
        w |= (unsigned long long)(kv.z && !tv.z) << (c * 4 + 2);
        w |= (unsigned long long)(kv.w && !tv.w) << (c * 4 + 3);
      }
    }
    mrow[r][half] = w;
  }

  const size_t abase = (size_t)((n0 >> 4) + wn * 4) * 8192 + (size_t)lane * 8;
  const size_t bbase = (size_t)((m0 >> 4) + wm * 4) * 8192 + (size_t)lane * 8;

  f32x4 acc[4][4] = {};
#pragma unroll
  for (int s = 0; s < 16; ++s) {
    bf16x8 aH[4], aL[4], bH[4], bL[4];
    LOADF(s, aH, aL, bH, bL, qhi, qlo, khi, klo);
    MFMAS(aH, aL, bH, bL);
  }
  __syncthreads();   // mask words ready (hidden under MFMA loop)

  // C/D layout: col = lane&15, row = (lane>>4)*4 + reg
  const int rbase = wn * 64 + (lane >> 4) * 4;
  const int cb15 = (lane & 15);

  float mv = NEGV; int mi = 0x7fffffff;
#pragma unroll
  for (int i = 0; i < 4; ++i) {
#pragma unroll
    for (int r = 0; r < 4; ++r) {
      int rl = rbase + i * 16 + r;
      unsigned long long ww = mrow[rl][wm];
      int gb = (n0 + rl) * NMS + m0;
#pragma unroll
      for (int j = 0; j < 4; ++j) {
        int bit = j * 16 + cb15;
        int cl = wm * 64 + bit;
        float sv = acc[i][j][r] * RSQRT_H;
        acc[i][j][r] = sv;
        bool valid = ((ww >> bit) & 1ull) != 0;
        if (valid && (sv > mv || (sv == mv && gb + cl < mi))) { mv = sv; mi = gb + cl; }
      }
    }
  }
  wreduce_maxidx(mv, mi);
  if ((t & 63) == 0) { s_rv[wid] = mv; s_ri[wid] = mi; }
  __syncthreads();
  if (t == 0) {
    float bm = s_rv[0]; int ba = s_ri[0];
    for (int w = 1; w < 4; ++w)
      if (s_rv[w] > bm || (s_rv[w] == bm && s_ri[w] < ba)) { bm = s_rv[w]; ba = s_ri[w]; }
    s_bm = bm; s_ba = ba;
  }
  __syncthreads();
  const float bm = s_bm;

  float se = 0.f;
#pragma unroll
  for (int i = 0; i < 4; ++i) {
#pragma unroll
    for (int r = 0; r < 4; ++r) {
      int rl = rbase + i * 16 + r;
      unsigned long long ww = mrow[rl][wm];
#pragma unroll
      for (int j = 0; j < 4; ++j) {
        int bit = j * 16 + cb15;
        bool valid = ((ww >> bit) & 1ull) != 0;
        if (valid) se += __expf(acc[i][j][r] - bm);
      }
    }
  }
  se = wreduce_sum(se);
  if ((t & 63) == 0) s_rs[wid] = se;
  __syncthreads();
  if (t == 0) {
    SPart pt;
    pt.m = s_bm;
    pt.s = s_rs[0] + s_rs[1] + s_rs[2] + s_rs[3];
    pt.a = s_ba; pt.pad = 0;
    parts[by * 32 + bx] = pt;
  }
}

// reduce 4096 partial Q vectors -> Qd[512] (f64), batched loads
__global__ __launch_bounds__(256) void qred_kernel(
    const double* __restrict__ qpart, double* __restrict__ Qd) {
  __shared__ double red[256];
  const int t = threadIdx.x;
  const int h = blockIdx.x * 16 + (t & 15);
  const int chunk = t >> 4;
  double s = 0.0;
  for (int j0 = 0; j0 < 256; j0 += 8) {
    double v[8];
#pragma unroll
    for (int u = 0; u < 8; ++u)
      v[u] = qpart[(size_t)(chunk * 256 + j0 + u) * HH + h];
#pragma unroll
    for (int u = 0; u < 8; ++u) s += v[u];
  }
  red[t] = s;
  __syncthreads();
  for (int off = 8; off > 0; off >>= 1) {
    if (chunk < off) red[t] += red[t + off * 16];
    __syncthreads();
  }
  if (t < 16) Qd[blockIdx.x * 16 + t] = red[t];
}

// tvec[h] = (Q @ var_Q_w.T)[h] + var_Q_b[h] + var_K_b[h]
__global__ __launch_bounds__(256) void prepmv_kernel(
    const double* __restrict__ Qd, const float* __restrict__ varQw,
    const float* __restrict__ varQb, const float* __restrict__ varKb,
    float* __restrict__ tvec) {
  __shared__ double red[256];
  const int t = threadIdx.x;
  const int h = blockIdx.x * 16 + (t & 15);
  const int chunk = t >> 4;
  const float* wrow = varQw + (size_t)h * HH + chunk * 32;
  const double* qd = Qd + chunk * 32;
  double s = 0.0;
  for (int j = 0; j < 32; ++j) s += qd[j] * (double)wrow[j];
  red[t] = s;
  __syncthreads();
  for (int off = 8; off > 0; off >>= 1) {
    if (chunk < off) red[t] += red[t + off * 16];
    __syncthreads();
  }
  if (t < 16) {
    int hh = blockIdx.x * 16 + t;
    tvec[hh] = (float)(red[t] + (double)varQb[hh] + (double)varKb[hh]);
  }
}

// ---------------------------------------------------------------------------
// K_t GEMM (lit @ varKw.T) via LDS-staged MFMA on pre-split frags; tanh epi.
__global__ __launch_bounds__(256, 2) void ktu_kernel(
    const u16* __restrict__ lithi, const u16* __restrict__ litlo,
    const u16* __restrict__ wkhi, const u16* __restrict__ wklo,
    const float* __restrict__ tvec, const float* __restrict__ attnw,
    float* __restrict__ upart) {
  __shared__ __align__(16) u16 lds[2][4][8][512];
  const int t = threadIdx.x, lane = t & 63, wid = t >> 6;
  const int wn = wid & 1, wm = wid >> 1;
  const int row0 = blockIdx.x * 128;
  const int l8 = lane * 8;

  const u16* sa = (wid == 0) ? lithi : (wid == 1) ? litlo : (wid == 2) ? wkhi : wklo;
  const int rb = (wid < 2) ? (row0 >> 4) : (blockIdx.y * 8);
  const u16* sab = sa + (size_t)rb * 8192 + l8;

#define KSTAGE(buf, s)                                                        \
  _Pragma("unroll") for (int f_ = 0; f_ < 8; ++f_)                            \
    stage_frag(sab + (size_t)f_ * 8192 + (size_t)(s) * 512,                   \
               &lds[buf][wid][f_][0]);

  KSTAGE(0, 0)
  f32x4 acc[4][4] = {};
#pragma unroll
  for (int s = 0; s < 16; ++s) {
    __syncthreads();
    if (s < 15) { KSTAGE((s + 1) & 1, s + 1) }
    const int b = s & 1;
    bf16x8 aH[4], aL[4], bH[4], bL[4];
#pragma unroll
    for (int f = 0; f < 4; ++f) {
      aH[f] = *(const bf16x8*)&lds[b][0][wn * 4 + f][l8];
      aL[f] = *(const bf16x8*)&lds[b][1][wn * 4 + f][l8];
      bH[f] = *(const bf16x8*)&lds[b][2][wm * 4 + f][l8];
      bL[f] = *(const bf16x8*)&lds[b][3][wm * 4 + f][l8];
    }
    MFMAS(aH, aL, bH, bL);
  }
#undef KSTAGE

  const int cbase = blockIdx.y * 128 + wm * 64;
  float tv[4], aw[4];
#pragma unroll
  for (int j = 0; j < 4; ++j) {
    int c = cbase + j * 16 + (lane & 15);
    tv[j] = tvec[c]; aw[j] = attnw[c];
  }
  float us[4][4];
#pragma unroll
  for (int i = 0; i < 4; ++i)
#pragma unroll
    for (int r = 0; r < 4; ++r) {
      float s = 0.f;
#pragma unroll
      for (int j = 0; j < 4; ++j) {
        float x = acc[i][j][r] + tv[j];
        float th = 1.0f - 2.0f / (__expf(2.0f * x) + 1.0f);   // safe tanh
        s += th * aw[j];
      }
      us[i][r] = s;
    }
#pragma unroll
  for (int m = 1; m < 16; m <<= 1)
#pragma unroll
    for (int i = 0; i < 4; ++i)
#pragma unroll
      for (int r = 0; r < 4; ++r) us[i][r] += __shfl_xor(us[i][r], m, 64);
  if ((lane & 15) == 0) {
#pragma unroll
    for (int i = 0; i < 4; ++i)
#pragma unroll
      for (int r = 0; r < 4; ++r) {
        int row = row0 + wn * 64 + i * 16 + (lane >> 4) * 4 + r;
        upart[(size_t)(blockIdx.y * 2 + wm) * NVARS + row] = us[i][r];
      }
  }
}

// ---------------------------------------------------------------------------
// u reduction stage 1: 64 blocks x 256 vars -> per-block {max, argmax, sumexp}.
__global__ __launch_bounds__(256) void usum_kernel(
    const float* __restrict__ upart, SPart* __restrict__ uparts2) {
  __shared__ float s_rv[4]; __shared__ int s_ri[4]; __shared__ float s_rs[4];
  __shared__ float s_bm; __shared__ int s_ba;
  const int t = threadIdx.x;
  const int i = blockIdx.x * 256 + t;
  float u = 0.f;
#pragma unroll
  for (int p = 0; p < 8; ++p) u += upart[(size_t)p * NVARS + i];
  float mv = u; int mi = i;
  wreduce_maxidx(mv, mi);
  if ((t & 63) == 0) { s_rv[t >> 6] = mv; s_ri[t >> 6] = mi; }
  __syncthreads();
  if (t == 0) {
    float bm = s_rv[0]; int ba = s_ri[0];
    for (int w = 1; w < 4; ++w)
      if (s_rv[w] > bm || (s_rv[w] == bm && s_ri[w] < ba)) { bm = s_rv[w]; ba = s_ri[w]; }
    s_bm = bm; s_ba = ba;
  }
  __syncthreads();
  float se = __expf(u - s_bm);
  se = wreduce_sum(se);
  if ((t & 63) == 0) s_rs[t >> 6] = se;
  __syncthreads();
  if (t == 0) {
    SPart p;
    p.m = s_bm;
    p.s = s_rs[0] + s_rs[1] + s_rs[2] + s_rs[3];
    p.a = s_ba; p.pad = 0;
    uparts2[blockIdx.x] = p;
  }
}

// ---------------------------------------------------------------------------
// Final combine.  d_out is FLOAT32 x4: {c_logp, pos_idx[ci], neg_idx[cj], var_idx}.
__global__ __launch_bounds__(256) void final_kernel(
    const SPart* __restrict__ uparts2, const SPart* __restrict__ parts,
    const int* __restrict__ pos_idx, const int* __restrict__ neg_idx,
    float* __restrict__ out) {
  __shared__ float s_rv[4]; __shared__ int s_ri[4]; __shared__ float s_rs[4];
  __shared__ float s_umax; __shared__ int s_uarg; __shared__ float s_usum;
  __shared__ float s_gm; __shared__ int s_ga;
  const int t = threadIdx.x;

  float mv = -3.0e38f; int mi = 0x7fffffff;
  SPart up;
  if (t < 64) {
    up = uparts2[t];
    mv = up.m; mi = up.a;
  }
  wreduce_maxidx(mv, mi);
  if ((t & 63) == 0) { s_rv[t >> 6] = mv; s_ri[t >> 6] = mi; }
  __syncthreads();
  if (t == 0) {
    float bm = s_rv[0]; int ba = s_ri[0];
    for (int w = 1; w < 4; ++w)
      if (s_rv[w] > bm || (s_rv[w] == bm && s_ri[w] < ba)) { bm = s_rv[w]; ba = s_ri[w]; }
    s_umax = bm; s_uarg = ba;
  }
  __syncthreads();
  float se = (t < 64) ? up.s * __expf(up.m - s_umax) : 0.f;
  se = wreduce_sum(se);
  if ((t & 63) == 0) s_rs[t >> 6] = se;
  __syncthreads();
  if (t == 0) s_usum = s_rs[0] + s_rs[1] + s_rs[2] + s_rs[3];
  __syncthreads();

  mv = NEGV; mi = 0x7fffffff;
  for (int i = t; i < 1024; i += 256) {
    SPart p = parts[i];
    if (p.m > mv || (p.m == mv && p.a < mi)) { mv = p.m; mi = p.a; }
  }
  wreduce_maxidx(mv, mi);
  if ((t & 63) == 0) { s_rv[t >> 6] = mv; s_ri[t >> 6] = mi; }
  __syncthreads();
  if (t == 0) {
    float bm = s_rv[0]; int ba = s_ri[0];
    for (int w = 1; w < 4; ++w)
      if (s_rv[w] > bm || (s_rv[w] == bm && s_ri[w] < ba)) { bm = s_rv[w]; ba = s_ri[w]; }
    s_gm = bm; s_ga = ba;
  }
  __syncthreads();
  const float gm = s_gm;
  float ss = 0.f;
  for (int i = t; i < 1024; i += 256) {
    SPart p = parts[i];
    ss += p.s * __expf(p.m - gm);
  }
  ss = wreduce_sum(ss);
  if ((t & 63) == 0) s_rs[t >> 6] = ss;
  __syncthreads();
  if (t == 0) {
    float gsum = s_rs[0] + s_rs[1] + s_rs[2] + s_rs[3];
    float c_logp = -logf(gsum) - logf(s_usum);
    int ga = s_ga;
    if (ga == 0x7fffffff) ga = 0;
    int ci = ga >> 12, cj = ga & 4095;
    out[0] = c_logp;
    out[1] = (float)pos_idx[ci];
    out[2] = (float)neg_idx[cj];
    out[3] = (float)s_uarg;
  }
}

extern "C" void kernel_launch(void* const* d_in, const int* in_sizes, int n_in,
                              void* d_out, int out_size, void* d_ws, size_t ws_size,
                              hipStream_t stream) {
  (void)in_sizes; (void)n_in; (void)out_size; (void)ws_size;
  const float* lit    = (const float*)d_in[0];
  const float* clause = (const float*)d_in[1];
  const int* pos_idx  = (const int*)d_in[2];
  const int* neg_idx  = (const int*)d_in[3];
  const void* keep    = d_in[4];
  const void* taken   = d_in[5];
  const float* varKw  = (const float*)d_in[6];
  const float* varKb  = (const float*)d_in[7];
  const float* varQw  = (const float*)d_in[8];
  const float* varQb  = (const float*)d_in[9];
  const float* attnw  = (const float*)d_in[10];
  // d_in[11] var_attn_b: uniform shift, cancels in log_softmax max/argmax
  const float* WQw    = (const float*)d_in[12];
  const float* WQb    = (const float*)d_in[13];
  const float* WKw    = (const float*)d_in[14];
  const float* WKb    = (const float*)d_in[15];

  char* ws = (char*)d_ws;
  size_t off = 0;
  auto alloc = [&](size_t b) {
    char* p = ws + off;
    off = (off + b + 255) & ~(size_t)255;
    return p;
  };
  double* qpart              = (double*)alloc((size_t)4096 * HH * 8);
  double* Qd                 = (double*)alloc(HH * 8);
  float* tvec                = (float*)alloc(HH * 4);
  float* upart               = (float*)alloc(8 * (size_t)NVARS * 4);
  u16* qhi                   = (u16*)alloc((size_t)NPOS * HH * 2);
  u16* qlo                   = (u16*)alloc((size_t)NPOS * HH * 2);
  u16* khi                   = (u16*)alloc((size_t)NMS * HH * 2);
  u16* klo                   = (u16*)alloc((size_t)NMS * HH * 2);
  u16* wkhi                  = (u16*)alloc((size_t)HH * HH * 2);
  u16* wklo                  = (u16*)alloc((size_t)HH * HH * 2);
  u16* pwqhi                 = (u16*)alloc((size_t)HH * HH * 2);
  u16* pwqlo                 = (u16*)alloc((size_t)HH * HH * 2);
  u16* pwkhi                 = (u16*)alloc((size_t)HH * HH * 2);
  u16* pwklo                 = (u16*)alloc((size_t)HH * HH * 2);
  u16* lithi                 = (u16*)alloc((size_t)NVARS * HH * 2);
  u16* litlo                 = (u16*)alloc((size_t)NVARS * HH * 2);
  SPart* parts               = (SPart*)alloc(1024 * sizeof(SPart));
  SPart* uparts2             = (SPart*)alloc(64 * sizeof(SPart));

  wtofrag_kernel<<<384, 256, 0, stream>>>(varKw, wkhi, wklo,
                                          WQw, pwqhi, pwqlo,
                                          WKw, pwkhi, pwklo);
  proj_kernel<<<dim3(32, 4, 2), 256, 0, stream>>>(clause, pos_idx, neg_idx,
                                                  pwqhi, pwqlo, pwkhi, pwklo,
                                                  WQb, WKb,
                                                  qhi, qlo, khi, klo);
  mega_kernel<<<7168, 256, 0, stream>>>(qhi, qlo, khi, klo, keep, taken, parts,
                                        clause, qpart, lit, lithi, litlo);
  qred_kernel<<<32, 256, 0, stream>>>(qpart, Qd);
  prepmv_kernel<<<32, 256, 0, stream>>>(Qd, varQw, varQb, varKb, tvec);
  ktu_kernel<<<dim3(128, 4), 256, 0, stream>>>(lithi, litlo, wkhi, wklo,
                                               tvec, attnw, upart);
  usum_kernel<<<64, 256, 0, stream>>>(upart, uparts2);
  final_kernel<<<1, 256, 0, stream>>>(uparts2, parts, pos_idx, neg_idx,
                                      (float*)d_out);
}

// Round 14
// 213.972 us; speedup vs baseline: 1.2069x; 1.2069x over previous
//
#include <hip/hip_runtime.h>
#include <hip/hip_bf16.h>
#include <math.h>

#define HH 512
#define NVARS 16384
#define NPOS 4096
#define NMS 4096
#define NEGV -1.0e30f
#define RSQRT_H 0.04419417382415922f   // 1/sqrt(512)

typedef unsigned short u16;
typedef unsigned char u8;
typedef __attribute__((ext_vector_type(8))) short bf16x8;
typedef __attribute__((ext_vector_type(4))) float f32x4;

struct SPart { float m; float s; int a; int pad; };

__device__ inline u16 f2bf(float f) {
  unsigned u = __float_as_uint(f);
  unsigned r = (u + 0x7fffu + ((u >> 16) & 1u)) >> 16;
  return (u16)r;
}
__device__ inline float bf2f(u16 h) { return __uint_as_float(((unsigned)h) << 16); }

__device__ inline void wreduce_maxidx(float& v, int& idx) {
#pragma unroll
  for (int m = 1; m < 64; m <<= 1) {
    float ov = __shfl_xor(v, m, 64);
    int oi = __shfl_xor(idx, m, 64);
    if (ov > v || (ov == v && oi < idx)) { v = ov; idx = oi; }
  }
}

__device__ inline float wreduce_sum(float v) {
#pragma unroll
  for (int m = 1; m < 64; m <<= 1) v += __shfl_xor(v, m, 64);
  return v;
}

// async global->LDS: 64 lanes x 16 B contiguous; dst wave-uniform.
__device__ __forceinline__ void stage_frag(const u16* src, u16* dst) {
  __builtin_amdgcn_global_load_lds(
      (const __attribute__((address_space(1))) void*)src,
      (__attribute__((address_space(3))) void*)dst, 16, 0, 0);
}

// row-major f32 [.. x 512] -> fragment-major bf16 hi/lo for one frag.
__device__ __forceinline__ void do_tofrag(
    const float* __restrict__ src, u16* __restrict__ hi, u16* __restrict__ lo,
    int frag, int lane) {
  const int R = frag >> 4, K = frag & 15;
  const float* p = src + (size_t)(R * 16 + (lane & 15)) * HH + K * 32 + (lane >> 4) * 8;
  float v[8];
  *(float4*)&v[0] = *(const float4*)p;
  *(float4*)&v[4] = *(const float4*)(p + 4);
  u16 h[8], l[8];
#pragma unroll
  for (int e = 0; e < 8; ++e) { h[e] = f2bf(v[e]); l[e] = f2bf(v[e] - bf2f(h[e])); }
  size_t base = (size_t)frag * 512 + (size_t)lane * 8;
  *(ushort4*)(hi + base) = *(ushort4*)&h[0];
  *(ushort4*)(hi + base + 4) = *(ushort4*)&h[4];
  *(ushort4*)(lo + base) = *(ushort4*)&l[0];
  *(ushort4*)(lo + base + 4) = *(ushort4*)&l[4];
}

// ---------------------------------------------------------------------------
// MFMA macros: pass-outer interleave; pass order hh, hl, lh preserved.
#define MFMA16(A, B)                                                                 \
  _Pragma("unroll") for (int i_ = 0; i_ < 4; ++i_)                                   \
  _Pragma("unroll") for (int j_ = 0; j_ < 4; ++j_)                                   \
    acc[i_][j_] = __builtin_amdgcn_mfma_f32_16x16x32_bf16(A[i_], B[j_], acc[i_][j_], 0, 0, 0);

#define MFMAS(AH, AL, BH, BL)                                                        \
  do { MFMA16(AH, BH) MFMA16(AH, BL) MFMA16(AL, BH) } while (0)

// ---------------------------------------------------------------------------
// weight tofrags: 3 matrices x 128 blocks
__global__ __launch_bounds__(256) void wtofrag_kernel(
    const float* __restrict__ varKw, u16* __restrict__ wkhi, u16* __restrict__ wklo,
    const float* __restrict__ WQw, u16* __restrict__ pwqhi, u16* __restrict__ pwqlo,
    const float* __restrict__ WKw, u16* __restrict__ pwkhi, u16* __restrict__ pwklo) {
  const int wb = blockIdx.x;
  const int m = wb >> 7;
  const int frag = (wb & 127) * 4 + (threadIdx.x >> 6);
  const float* src = (m == 0) ? varKw : (m == 1) ? WQw : WKw;
  u16* hi = (m == 0) ? wkhi : (m == 1) ? pwqhi : pwkhi;
  u16* lo = (m == 0) ? wklo : (m == 1) ? pwqlo : pwklo;
  do_tofrag(src, hi, lo, frag, threadIdx.x & 63);
}

// ---------------------------------------------------------------------------
// megaA: LDS-light co-schedule of proj (compute) with qsum + lit tofrag
// (streaming).  ids [0,256)->proj, [256,2304)->qsum, [2304,6400)->littofrag.
__global__ __launch_bounds__(256, 3) void megaA_kernel(
    const float* __restrict__ clause,
    const int* __restrict__ pos_idx, const int* __restrict__ neg_idx,
    const u16* __restrict__ pwqhi, const u16* __restrict__ pwqlo,
    const u16* __restrict__ pwkhi, const u16* __restrict__ pwklo,
    const float* __restrict__ bQ, const float* __restrict__ bK,
    u16* __restrict__ qhi, u16* __restrict__ qlo,
    u16* __restrict__ khi, u16* __restrict__ klo,
    double* __restrict__ qpart,
    const float* __restrict__ lit, u16* __restrict__ lithi, u16* __restrict__ litlo) {
  const int id = blockIdx.x;
  const int t = threadIdx.x;
  const int lane = t & 63, wid = t >> 6;

  if (id >= 2304) {
    // ---- lit tofrag ----
    const int frag = (id - 2304) * 4 + wid;
    do_tofrag(lit, lithi, litlo, frag, lane);
    return;
  }
  if (id >= 256) {
    // ---- qsum: 32 rows/block, 16 float4 loads batched ----
    const int qb = id - 256;                // [0,2048)
    const int fg = t & 127;
    const int rh = t >> 7;
    const float* base = clause + ((size_t)qb * 32 + rh * 16) * HH + fg * 4;
    float4 v[16];
#pragma unroll
    for (int u = 0; u < 16; ++u)
      v[u] = *(const float4*)(base + (size_t)u * HH);
    double a0 = 0.0, a1 = 0.0, a2 = 0.0, a3 = 0.0;
#pragma unroll
    for (int u = 0; u < 16; ++u) {
      a0 += (double)v[u].x; a1 += (double)v[u].y;
      a2 += (double)v[u].z; a3 += (double)v[u].w;
    }
    double* o = qpart + (size_t)(qb * 2 + rh) * HH + fg * 4;
    o[0] = a0; o[1] = a1; o[2] = a2; o[3] = a3;
    return;
  }

  // ---- proj (ids [0,256)): A = W frags, B = gathered clause (otf split) ----
  const int pid = id;
  const int rowt = pid & 31, colt = (pid >> 5) & 3, z = pid >> 7;
  const int* __restrict__ idx = z ? neg_idx : pos_idx;
  const u16* __restrict__ whp = z ? pwkhi : pwqhi;
  const u16* __restrict__ wlp = z ? pwklo : pwqlo;
  const float* __restrict__ bias = z ? bK : bQ;
  u16* __restrict__ ohi = z ? khi : qhi;
  u16* __restrict__ olo = z ? klo : qlo;

  const int wn = wid & 1, wm = wid >> 1;
  const int row0 = rowt * 128;
  const int col0 = colt * 128;

  const float* bptr[4];
#pragma unroll
  for (int j = 0; j < 4; ++j) {
    int g = idx[row0 + wn * 64 + j * 16 + (lane & 15)];
    bptr[j] = clause + (size_t)g * HH + (lane >> 4) * 8;
  }
  const size_t abase = (size_t)((col0 >> 4) + wm * 4) * 8192 + (size_t)lane * 8;

  f32x4 acc[4][4] = {};
#pragma unroll
  for (int s = 0; s < 16; ++s) {
    float rB[4][8];
    bf16x8 aH[4], aL[4], bH[4], bL[4];
#pragma unroll
    for (int f = 0; f < 4; ++f) {
      *(float4*)&rB[f][0] = *(const float4*)(bptr[f] + s * 32);
      *(float4*)&rB[f][4] = *(const float4*)(bptr[f] + s * 32 + 4);
      size_t oa = abase + (size_t)f * 8192 + (size_t)s * 512;
      aH[f] = *(const bf16x8*)(whp + oa);
      aL[f] = *(const bf16x8*)(wlp + oa);
    }
#pragma unroll
    for (int f = 0; f < 4; ++f)
#pragma unroll
      for (int e = 0; e < 8; ++e) {
        float v = rB[f][e];
        u16 h = f2bf(v);
        bH[f][e] = (short)h;
        bL[f][e] = (short)f2bf(v - bf2f(h));
      }
    MFMA16(aH, bH)
    MFMA16(aL, bH)
    MFMA16(aH, bL)
  }

  const int q4 = lane >> 4;
#pragma unroll
  for (int i = 0; i < 4; ++i) {
    const int hbase = col0 + wm * 64 + i * 16 + q4 * 4;
    float b0 = bias[hbase + 0], b1 = bias[hbase + 1];
    float b2 = bias[hbase + 2], b3 = bias[hbase + 3];
    const int lane16 = (lane & 15) + ((i & 1) * 2 + (q4 >> 1)) * 16;
    const int sub = (q4 & 1) * 4;
#pragma unroll
    for (int j = 0; j < 4; ++j) {
      const int frag = ((row0 + wn * 64 + j * 16) >> 4) * 16 +
                       ((col0 + wm * 64 + i * 16) >> 5);
      size_t base = (size_t)frag * 512 + (size_t)lane16 * 8 + sub;
      ushort4 hv, lv;
      float v;
      v = acc[i][j][0] + b0; hv.x = f2bf(v); lv.x = f2bf(v - bf2f(hv.x));
      v = acc[i][j][1] + b1; hv.y = f2bf(v); lv.y = f2bf(v - bf2f(hv.y));
      v = acc[i][j][2] + b2; hv.z = f2bf(v); lv.z = f2bf(v - bf2f(hv.z));
      v = acc[i][j][3] + b3; hv.w = f2bf(v); lv.w = f2bf(v - bf2f(hv.w));
      *(ushort4*)(ohi + base) = hv;
      *(ushort4*)(olo + base) = lv;
    }
  }
}

// reduce 4096 partial Q vectors -> Qd[512] (f64), batched loads
__global__ __launch_bounds__(256) void qred_kernel(
    const double* __restrict__ qpart, double* __restrict__ Qd) {
  __shared__ double red[256];
  const int t = threadIdx.x;
  const int h = blockIdx.x * 16 + (t & 15);
  const int chunk = t >> 4;
  double s = 0.0;
  for (int j0 = 0; j0 < 256; j0 += 8) {
    double v[8];
#pragma unroll
    for (int u = 0; u < 8; ++u)
      v[u] = qpart[(size_t)(chunk * 256 + j0 + u) * HH + h];
#pragma unroll
    for (int u = 0; u < 8; ++u) s += v[u];
  }
  red[t] = s;
  __syncthreads();
  for (int off = 8; off > 0; off >>= 1) {
    if (chunk < off) red[t] += red[t + off * 16];
    __syncthreads();
  }
  if (t < 16) Qd[blockIdx.x * 16 + t] = red[t];
}

// tvec[h] = (Q @ var_Q_w.T)[h] + var_Q_b[h] + var_K_b[h]
__global__ __launch_bounds__(256) void prepmv_kernel(
    const double* __restrict__ Qd, const float* __restrict__ varQw,
    const float* __restrict__ varQb, const float* __restrict__ varKb,
    float* __restrict__ tvec) {
  __shared__ double red[256];
  const int t = threadIdx.x;
  const int h = blockIdx.x * 16 + (t & 15);
  const int chunk = t >> 4;
  const float* wrow = varQw + (size_t)h * HH + chunk * 32;
  const double* qd = Qd + chunk * 32;
  double s = 0.0;
  for (int j = 0; j < 32; ++j) s += qd[j] * (double)wrow[j];
  red[t] = s;
  __syncthreads();
  for (int off = 8; off > 0; off >>= 1) {
    if (chunk < off) red[t] += red[t + off * 16];
    __syncthreads();
  }
  if (t < 16) {
    int hh = blockIdx.x * 16 + t;
    tvec[hh] = (float)(red[t] + (double)varQb[hh] + (double)varKb[hh]);
  }
}

// ---------------------------------------------------------------------------
// megaB: co-schedule of the two LDS-staged MFMA pipelines.
// ids [0,1024) -> scores (with INLINE mask build from keep/taken — the 32x32
// block grid tiles the mask exactly once, absorbing pack for free);
// ids [1024,1536) -> ktu (tanh epilogue).
__global__ __launch_bounds__(256, 2) void megaB_kernel(
    const u16* __restrict__ qhi, const u16* __restrict__ qlo,
    const u16* __restrict__ khi, const u16* __restrict__ klo,
    const void* __restrict__ keep, const void* __restrict__ taken,
    SPart* __restrict__ parts,
    const u16* __restrict__ lithi, const u16* __restrict__ litlo,
    const u16* __restrict__ wkhi, const u16* __restrict__ wklo,
    const float* __restrict__ tvec, const float* __restrict__ attnw,
    float* __restrict__ upart) {
  __shared__ __align__(16) u16 lds[2][4][8][512];
  __shared__ unsigned long long mrow[128][2];
  __shared__ float s_rv[4]; __shared__ int s_ri[4]; __shared__ float s_rs[4];
  __shared__ float s_bm; __shared__ int s_ba;

  const int id = blockIdx.x;
  const int t = threadIdx.x;
  const int lane = t & 63;
  const int wid = t >> 6;
  const int wn = wid & 1, wm = wid >> 1;
  const int l8 = lane * 8;

  if (id >= 1024) {
    // ---- ktu: K_t GEMM (lit @ varKw.T), LDS-staged; tanh epilogue ----
    const int kb = id - 1024;               // [0,512)
    const int rowt = kb >> 2, ht = kb & 3;
    const int row0 = rowt * 128;

    const u16* sa = (wid == 0) ? lithi : (wid == 1) ? litlo : (wid == 2) ? wkhi : wklo;
    const int rb = (wid < 2) ? (row0 >> 4) : (ht * 8);
    const u16* sab = sa + (size_t)rb * 8192 + l8;

#define KSTAGE(buf, s)                                                        \
    _Pragma("unroll") for (int f_ = 0; f_ < 8; ++f_)                          \
      stage_frag(sab + (size_t)f_ * 8192 + (size_t)(s) * 512,                 \
                 &lds[buf][wid][f_][0]);

    KSTAGE(0, 0)
    f32x4 acc[4][4] = {};
#pragma unroll
    for (int s = 0; s < 16; ++s) {
      __syncthreads();
      if (s < 15) { KSTAGE((s + 1) & 1, s + 1) }
      const int b = s & 1;
      bf16x8 aH[4], aL[4], bH[4], bL[4];
#pragma unroll
      for (int f = 0; f < 4; ++f) {
        aH[f] = *(const bf16x8*)&lds[b][0][wn * 4 + f][l8];
        aL[f] = *(const bf16x8*)&lds[b][1][wn * 4 + f][l8];
        bH[f] = *(const bf16x8*)&lds[b][2][wm * 4 + f][l8];
        bL[f] = *(const bf16x8*)&lds[b][3][wm * 4 + f][l8];
      }
      MFMAS(aH, aL, bH, bL);
    }
#undef KSTAGE

    const int cbase = ht * 128 + wm * 64;
    float tv[4], aw[4];
#pragma unroll
    for (int j = 0; j < 4; ++j) {
      int c = cbase + j * 16 + (lane & 15);
      tv[j] = tvec[c]; aw[j] = attnw[c];
    }
    float us[4][4];
#pragma unroll
    for (int i = 0; i < 4; ++i)
#pragma unroll
      for (int r = 0; r < 4; ++r) {
        float s = 0.f;
#pragma unroll
        for (int j = 0; j < 4; ++j) {
          float x = acc[i][j][r] + tv[j];
          float th = 1.0f - 2.0f / (__expf(2.0f * x) + 1.0f);   // safe tanh
          s += th * aw[j];
        }
        us[i][r] = s;
      }
#pragma unroll
    for (int m = 1; m < 16; m <<= 1)
#pragma unroll
      for (int i = 0; i < 4; ++i)
#pragma unroll
        for (int r = 0; r < 4; ++r) us[i][r] += __shfl_xor(us[i][r], m, 64);
    if ((lane & 15) == 0) {
#pragma unroll
      for (int i = 0; i < 4; ++i)
#pragma unroll
        for (int r = 0; r < 4; ++r) {
          int row = row0 + wn * 64 + i * 16 + (lane >> 4) * 4 + r;
          upart[(size_t)(ht * 2 + wm) * NVARS + row] = us[i][r];
        }
    }
    return;
  }

  // ---- scores (ids [0,1024)): LDS-staged 3-pass split MFMA + swizzle ----
  const int bid = id;
  const int xcd = bid & 7, p = bid >> 3;
  const int sp = p >> 6, q = p & 63;
  const int g = xcd * 2 + sp;
  const int bx = (g & 3) * 8 + (q & 7);
  const int by = (g >> 2) * 8 + (q >> 3);

  const int n0 = by * 128;
  const int m0 = bx * 128;

  // inline mask build: thread t covers row t>>1, col-half t&1 (pack absorbed)
  {
    const int r = t >> 1, half = t & 1;
    const unsigned* kw = (const unsigned*)keep;
    int f = 1;
#pragma unroll
    for (int i = 0; i < 16; ++i) f &= (kw[i] <= 1u);
    unsigned long long w = 0;
    if (!f) {
      const u8* kp = (const u8*)keep + (size_t)(n0 + r) * NMS + m0 + half * 64;
      const u8* tp = (const u8*)taken + (size_t)(n0 + r) * NMS + m0 + half * 64;
#pragma unroll
      for (int c = 0; c < 4; ++c) {
        uint4 kv = *(const uint4*)(kp + c * 16);
        uint4 tv = *(const uint4*)(tp + c * 16);
        unsigned kws[4] = {kv.x, kv.y, kv.z, kv.w};
        unsigned tws[4] = {tv.x, tv.y, tv.z, tv.w};
#pragma unroll
        for (int wi = 0; wi < 4; ++wi)
#pragma unroll
          for (int y = 0; y < 4; ++y) {
            unsigned kb = (kws[wi] >> (8 * y)) & 0xffu;
            unsigned tb = (tws[wi] >> (8 * y)) & 0xffu;
            w |= (unsigned long long)(kb && !tb) << (c * 16 + wi * 4 + y);
          }
      }
    } else {
      const unsigned* kp = (const unsigned*)keep + (size_t)(n0 + r) * NMS + m0 + half * 64;
      const unsigned* tp = (const unsigned*)taken + (size_t)(n0 + r) * NMS + m0 + half * 64;
#pragma unroll
      for (int c = 0; c < 16; ++c) {
        uint4 kv = *(const uint4*)(kp + c * 4);
        uint4 tv = *(const uint4*)(tp + c * 4);
        w |= (unsigned long long)(kv.x && !tv.x) << (c * 4 + 0);
        w |= (unsigned long long)(kv.y && !tv.y) << (c * 4 + 1);
        w |= (unsigned long long)(kv.z && !tv.z) << (c * 4 + 2);
        w |= (unsigned long long)(kv.w && !tv.w) << (c * 4 + 3);
      }
    }
    mrow[r][half] = w;
  }

  const u16* sa = (wid == 0) ? qhi : (wid == 1) ? qlo : (wid == 2) ? khi : klo;
  const int rb = (wid < 2) ? (n0 >> 4) : (m0 >> 4);
  const u16* sab = sa + (size_t)rb * 8192 + l8;

#define SSTAGE(buf, s)                                                        \
  _Pragma("unroll") for (int f_ = 0; f_ < 8; ++f_)                            \
    stage_frag(sab + (size_t)f_ * 8192 + (size_t)(s) * 512,                   \
               &lds[buf][wid][f_][0]);

  SSTAGE(0, 0)
  f32x4 acc[4][4] = {};
#pragma unroll
  for (int s = 0; s < 16; ++s) {
    __syncthreads();
    if (s < 15) { SSTAGE((s + 1) & 1, s + 1) }
    const int b = s & 1;
    bf16x8 aH[4], aL[4], bH[4], bL[4];
#pragma unroll
    for (int f = 0; f < 4; ++f) {
      aH[f] = *(const bf16x8*)&lds[b][0][wn * 4 + f][l8];
      aL[f] = *(const bf16x8*)&lds[b][1][wn * 4 + f][l8];
      bH[f] = *(const bf16x8*)&lds[b][2][wm * 4 + f][l8];
      bL[f] = *(const bf16x8*)&lds[b][3][wm * 4 + f][l8];
    }
    MFMAS(aH, aL, bH, bL);
  }
#undef SSTAGE

  // C/D layout: col = lane&15, row = (lane>>4)*4 + reg
  const int rbase = wn * 64 + (lane >> 4) * 4;
  const int cb15 = (lane & 15);

  float mv = NEGV; int mi = 0x7fffffff;
#pragma unroll
  for (int i = 0; i < 4; ++i) {
#pragma unroll
    for (int r = 0; r < 4; ++r) {
      int rl = rbase + i * 16 + r;
      unsigned long long ww = mrow[rl][wm];
      int gb = (n0 + rl) * NMS + m0;
#pragma unroll
      for (int j = 0; j < 4; ++j) {
        int bit = j * 16 + cb15;
        int cl = wm * 64 + bit;
        float sv = acc[i][j][r] * RSQRT_H;
        acc[i][j][r] = sv;
        bool valid = ((ww >> bit) & 1ull) != 0;
        if (valid && (sv > mv || (sv == mv && gb + cl < mi))) { mv = sv; mi = gb + cl; }
      }
    }
  }
  wreduce_maxidx(mv, mi);
  if ((t & 63) == 0) { s_rv[wid] = mv; s_ri[wid] = mi; }
  __syncthreads();
  if (t == 0) {
    float bm = s_rv[0]; int ba = s_ri[0];
    for (int w = 1; w < 4; ++w)
      if (s_rv[w] > bm || (s_rv[w] == bm && s_ri[w] < ba)) { bm = s_rv[w]; ba = s_ri[w]; }
    s_bm = bm; s_ba = ba;
  }
  __syncthreads();
  const float bm = s_bm;

  float se = 0.f;
#pragma unroll
  for (int i = 0; i < 4; ++i) {
#pragma unroll
    for (int r = 0; r < 4; ++r) {
      int rl = rbase + i * 16 + r;
      unsigned long long ww = mrow[rl][wm];
#pragma unroll
      for (int j = 0; j < 4; ++j) {
        int bit = j * 16 + cb15;
        bool valid = ((ww >> bit) & 1ull) != 0;
        if (valid) se += __expf(acc[i][j][r] - bm);
      }
    }
  }
  se = wreduce_sum(se);
  if ((t & 63) == 0) s_rs[wid] = se;
  __syncthreads();
  if (t == 0) {
    SPart pt;
    pt.m = s_bm;
    pt.s = s_rs[0] + s_rs[1] + s_rs[2] + s_rs[3];
    pt.a = s_ba; pt.pad = 0;
    parts[by * 32 + bx] = pt;
  }
}

// ---------------------------------------------------------------------------
// u reduction stage 1: 64 blocks x 256 vars -> per-block {max, argmax, sumexp}.
__global__ __launch_bounds__(256) void usum_kernel(
    const float* __restrict__ upart, SPart* __restrict__ uparts2) {
  __shared__ float s_rv[4]; __shared__ int s_ri[4]; __shared__ float s_rs[4];
  __shared__ float s_bm; __shared__ int s_ba;
  const int t = threadIdx.x;
  const int i = blockIdx.x * 256 + t;
  float u = 0.f;
#pragma unroll
  for (int p = 0; p < 8; ++p) u += upart[(size_t)p * NVARS + i];
  float mv = u; int mi = i;
  wreduce_maxidx(mv, mi);
  if ((t & 63) == 0) { s_rv[t >> 6] = mv; s_ri[t >> 6] = mi; }
  __syncthreads();
  if (t == 0) {
    float bm = s_rv[0]; int ba = s_ri[0];
    for (int w = 1; w < 4; ++w)
      if (s_rv[w] > bm || (s_rv[w] == bm && s_ri[w] < ba)) { bm = s_rv[w]; ba = s_ri[w]; }
    s_bm = bm; s_ba = ba;
  }
  __syncthreads();
  float se = __expf(u - s_bm);
  se = wreduce_sum(se);
  if ((t & 63) == 0) s_rs[t >> 6] = se;
  __syncthreads();
  if (t == 0) {
    SPart p;
    p.m = s_bm;
    p.s = s_rs[0] + s_rs[1] + s_rs[2] + s_rs[3];
    p.a = s_ba; p.pad = 0;
    uparts2[blockIdx.x] = p;
  }
}

// ---------------------------------------------------------------------------
// Final combine.  d_out is FLOAT32 x4: {c_logp, pos_idx[ci], neg_idx[cj], var_idx}.
__global__ __launch_bounds__(256) void final_kernel(
    const SPart* __restrict__ uparts2, const SPart* __restrict__ parts,
    const int* __restrict__ pos_idx, const int* __restrict__ neg_idx,
    float* __restrict__ out) {
  __shared__ float s_rv[4]; __shared__ int s_ri[4]; __shared__ float s_rs[4];
  __shared__ float s_umax; __shared__ int s_uarg; __shared__ float s_usum;
  __shared__ float s_gm; __shared__ int s_ga;
  const int t = threadIdx.x;

  float mv = -3.0e38f; int mi = 0x7fffffff;
  SPart up;
  if (t < 64) {
    up = uparts2[t];
    mv = up.m; mi = up.a;
  }
  wreduce_maxidx(mv, mi);
  if ((t & 63) == 0) { s_rv[t >> 6] = mv; s_ri[t >> 6] = mi; }
  __syncthreads();
  if (t == 0) {
    float bm = s_rv[0]; int ba = s_ri[0];
    for (int w = 1; w < 4; ++w)
      if (s_rv[w] > bm || (s_rv[w] == bm && s_ri[w] < ba)) { bm = s_rv[w]; ba = s_ri[w]; }
    s_umax = bm; s_uarg = ba;
  }
  __syncthreads();
  float se = (t < 64) ? up.s * __expf(up.m - s_umax) : 0.f;
  se = wreduce_sum(se);
  if ((t & 63) == 0) s_rs[t >> 6] = se;
  __syncthreads();
  if (t == 0) s_usum = s_rs[0] + s_rs[1] + s_rs[2] + s_rs[3];
  __syncthreads();

  mv = NEGV; mi = 0x7fffffff;
  for (int i = t; i < 1024; i += 256) {
    SPart p = parts[i];
    if (p.m > mv || (p.m == mv && p.a < mi)) { mv = p.m; mi = p.a; }
  }
  wreduce_maxidx(mv, mi);
  if ((t & 63) == 0) { s_rv[t >> 6] = mv; s_ri[t >> 6] = mi; }
  __syncthreads();
  if (t == 0) {
    float bm = s_rv[0]; int ba = s_ri[0];
    for (int w = 1; w < 4; ++w)
      if (s_rv[w] > bm || (s_rv[w] == bm && s_ri[w] < ba)) { bm = s_rv[w]; ba = s_ri[w]; }
    s_gm = bm; s_ga = ba;
  }
  __syncthreads();
  const float gm = s_gm;
  float ss = 0.f;
  for (int i = t; i < 1024; i += 256) {
    SPart p = parts[i];
    ss += p.s * __expf(p.m - gm);
  }
  ss = wreduce_sum(ss);
  if ((t & 63) == 0) s_rs[t >> 6] = ss;
  __syncthreads();
  if (t == 0) {
    float gsum = s_rs[0] + s_rs[1] + s_rs[2] + s_rs[3];
    float c_logp = -logf(gsum) - logf(s_usum);
    int ga = s_ga;
    if (ga == 0x7fffffff) ga = 0;
    int ci = ga >> 12, cj = ga & 4095;
    out[0] = c_logp;
    out[1] = (float)pos_idx[ci];
    out[2] = (float)neg_idx[cj];
    out[3] = (float)s_uarg;
  }
}

extern "C" void kernel_launch(void* const* d_in, const int* in_sizes, int n_in,
                              void* d_out, int out_size, void* d_ws, size_t ws_size,
                              hipStream_t stream) {
  (void)in_sizes; (void)n_in; (void)out_size; (void)ws_size;
  const float* lit    = (const float*)d_in[0];
  const float* clause = (const float*)d_in[1];
  const int* pos_idx  = (const int*)d_in[2];
  const int* neg_idx  = (const int*)d_in[3];
  const void* keep    = d_in[4];
  const void* taken   = d_in[5];
  const float* varKw  = (const float*)d_in[6];
  const float* varKb  = (const float*)d_in[7];
  const float* varQw  = (const float*)d_in[8];
  const float* varQb  = (const float*)d_in[9];
  const float* attnw  = (const float*)d_in[10];
  // d_in[11] var_attn_b: uniform shift, cancels in log_softmax max/argmax
  const float* WQw    = (const float*)d_in[12];
  const float* WQb    = (const float*)d_in[13];
  const float* WKw    = (const float*)d_in[14];
  const float* WKb    = (const float*)d_in[15];

  char* ws = (char*)d_ws;
  size_t off = 0;
  auto alloc = [&](size_t b) {
    char* p = ws + off;
    off = (off + b + 255) & ~(size_t)255;
    return p;
  };
  double* qpart              = (double*)alloc((size_t)4096 * HH * 8);
  double* Qd                 = (double*)alloc(HH * 8);
  float* tvec                = (float*)alloc(HH * 4);
  float* upart               = (float*)alloc(8 * (size_t)NVARS * 4);
  u16* qhi                   = (u16*)alloc((size_t)NPOS * HH * 2);
  u16* qlo                   = (u16*)alloc((size_t)NPOS * HH * 2);
  u16* khi                   = (u16*)alloc((size_t)NMS * HH * 2);
  u16* klo                   = (u16*)alloc((size_t)NMS * HH * 2);
  u16* wkhi                  = (u16*)alloc((size_t)HH * HH * 2);
  u16* wklo                  = (u16*)alloc((size_t)HH * HH * 2);
  u16* pwqhi                 = (u16*)alloc((size_t)HH * HH * 2);
  u16* pwqlo                 = (u16*)alloc((size_t)HH * HH * 2);
  u16* pwkhi                 = (u16*)alloc((size_t)HH * HH * 2);
  u16* pwklo                 = (u16*)alloc((size_t)HH * HH * 2);
  u16* lithi                 = (u16*)alloc((size_t)NVARS * HH * 2);
  u16* litlo                 = (u16*)alloc((size_t)NVARS * HH * 2);
  SPart* parts               = (SPart*)alloc(1024 * sizeof(SPart));
  SPart* uparts2             = (SPart*)alloc(64 * sizeof(SPart));

  wtofrag_kernel<<<384, 256, 0, stream>>>(varKw, wkhi, wklo,
                                          WQw, pwqhi, pwqlo,
                                          WKw, pwkhi, pwklo);
  megaA_kernel<<<6400, 256, 0, stream>>>(clause, pos_idx, neg_idx,
                                         pwqhi, pwqlo, pwkhi, pwklo,
                                         WQb, WKb, qhi, qlo, khi, klo,
                                         qpart, lit, lithi, litlo);
  qred_kernel<<<32, 256, 0, stream>>>(qpart, Qd);
  prepmv_kernel<<<32, 256, 0, stream>>>(Qd, varQw, varQb, varKb, tvec);
  megaB_kernel<<<1536, 256, 0, stream>>>(qhi, qlo, khi, klo, keep, taken, parts,
                                         lithi, litlo, wkhi, wklo,
                                         tvec, attnw, upart);
  usum_kernel<<<64, 256, 0, stream>>>(upart, uparts2);
  final_kernel<<<1, 256, 0, stream>>>(uparts2, parts, pos_idx, neg_idx,
                                      (float*)d_out);
}

// Round 15
// 212.240 us; speedup vs baseline: 1.2167x; 1.0082x over previous
//
#include <hip/hip_runtime.h>
#include <hip/hip_bf16.h>
#include <math.h>

#define HH 512
#define NVARS 16384
#define NPOS 4096
#define NMS 4096
#define NEGV -1.0e30f
#define RSQRT_H 0.04419417382415922f   // 1/sqrt(512)

typedef unsigned short u16;
typedef unsigned char u8;
typedef __attribute__((ext_vector_type(8))) short bf16x8;
typedef __attribute__((ext_vector_type(4))) float f32x4;

struct SPart { float m; float s; int a; int pad; };

__device__ inline u16 f2bf(float f) {
  unsigned u = __float_as_uint(f);
  unsigned r = (u + 0x7fffu + ((u >> 16) & 1u)) >> 16;
  return (u16)r;
}
__device__ inline float bf2f(u16 h) { return __uint_as_float(((unsigned)h) << 16); }

__device__ inline void wreduce_maxidx(float& v, int& idx) {
#pragma unroll
  for (int m = 1; m < 64; m <<= 1) {
    float ov = __shfl_xor(v, m, 64);
    int oi = __shfl_xor(idx, m, 64);
    if (ov > v || (ov == v && oi < idx)) { v = ov; idx = oi; }
  }
}

__device__ inline float wreduce_sum(float v) {
#pragma unroll
  for (int m = 1; m < 64; m <<= 1) v += __shfl_xor(v, m, 64);
  return v;
}

// async global->LDS: 64 lanes x 16 B contiguous; dst wave-uniform.
__device__ __forceinline__ void stage_frag(const u16* src, u16* dst) {
  __builtin_amdgcn_global_load_lds(
      (const __attribute__((address_space(1))) void*)src,
      (__attribute__((address_space(3))) void*)dst, 16, 0, 0);
}

// row-major f32 [.. x 512] -> fragment-major bf16 hi/lo for one frag.
__device__ __forceinline__ void do_tofrag(
    const float* __restrict__ src, u16* __restrict__ hi, u16* __restrict__ lo,
    int frag, int lane) {
  const int R = frag >> 4, K = frag & 15;
  const float* p = src + (size_t)(R * 16 + (lane & 15)) * HH + K * 32 + (lane >> 4) * 8;
  float v[8];
  *(float4*)&v[0] = *(const float4*)p;
  *(float4*)&v[4] = *(const float4*)(p + 4);
  u16 h[8], l[8];
#pragma unroll
  for (int e = 0; e < 8; ++e) { h[e] = f2bf(v[e]); l[e] = f2bf(v[e] - bf2f(h[e])); }
  size_t base = (size_t)frag * 512 + (size_t)lane * 8;
  *(ushort4*)(hi + base) = *(ushort4*)&h[0];
  *(ushort4*)(hi + base + 4) = *(ushort4*)&h[4];
  *(ushort4*)(lo + base) = *(ushort4*)&l[0];
  *(ushort4*)(lo + base + 4) = *(ushort4*)&l[4];
}

// ---------------------------------------------------------------------------
// MFMA macros: pass-outer interleave; pass order hh, hl, lh preserved.
#define MFMA16(A, B)                                                                 \
  _Pragma("unroll") for (int i_ = 0; i_ < 4; ++i_)                                   \
  _Pragma("unroll") for (int j_ = 0; j_ < 4; ++j_)                                   \
    acc[i_][j_] = __builtin_amdgcn_mfma_f32_16x16x32_bf16(A[i_], B[j_], acc[i_][j_], 0, 0, 0);

#define MFMAS(AH, AL, BH, BL)                                                        \
  do { MFMA16(AH, BH) MFMA16(AH, BL) MFMA16(AL, BH) } while (0)

// ---------------------------------------------------------------------------
// weight tofrags: 3 matrices x 128 blocks
__global__ __launch_bounds__(256) void wtofrag_kernel(
    const float* __restrict__ varKw, u16* __restrict__ wkhi, u16* __restrict__ wklo,
    const float* __restrict__ WQw, u16* __restrict__ pwqhi, u16* __restrict__ pwqlo,
    const float* __restrict__ WKw, u16* __restrict__ pwkhi, u16* __restrict__ pwklo) {
  const int wb = blockIdx.x;
  const int m = wb >> 7;
  const int frag = (wb & 127) * 4 + (threadIdx.x >> 6);
  const float* src = (m == 0) ? varKw : (m == 1) ? WQw : WKw;
  u16* hi = (m == 0) ? wkhi : (m == 1) ? pwqhi : pwkhi;
  u16* lo = (m == 0) ? wklo : (m == 1) ? pwqlo : pwklo;
  do_tofrag(src, hi, lo, frag, threadIdx.x & 63);
}

// ---------------------------------------------------------------------------
// megaA: LDS-light co-schedule of proj (compute) with qsum + lit tofrag
// (streaming).  ids [0,256)->proj, [256,2304)->qsum, [2304,6400)->littofrag.
__global__ __launch_bounds__(256, 3) void megaA_kernel(
    const float* __restrict__ clause,
    const int* __restrict__ pos_idx, const int* __restrict__ neg_idx,
    const u16* __restrict__ pwqhi, const u16* __restrict__ pwqlo,
    const u16* __restrict__ pwkhi, const u16* __restrict__ pwklo,
    const float* __restrict__ bQ, const float* __restrict__ bK,
    u16* __restrict__ qhi, u16* __restrict__ qlo,
    u16* __restrict__ khi, u16* __restrict__ klo,
    double* __restrict__ qpart,
    const float* __restrict__ lit, u16* __restrict__ lithi, u16* __restrict__ litlo) {
  const int id = blockIdx.x;
  const int t = threadIdx.x;
  const int lane = t & 63, wid = t >> 6;

  if (id >= 2304) {
    // ---- lit tofrag ----
    const int frag = (id - 2304) * 4 + wid;
    do_tofrag(lit, lithi, litlo, frag, lane);
    return;
  }
  if (id >= 256) {
    // ---- qsum: 32 rows/block, 16 float4 loads batched ----
    const int qb = id - 256;                // [0,2048)
    const int fg = t & 127;
    const int rh = t >> 7;
    const float* base = clause + ((size_t)qb * 32 + rh * 16) * HH + fg * 4;
    float4 v[16];
#pragma unroll
    for (int u = 0; u < 16; ++u)
      v[u] = *(const float4*)(base + (size_t)u * HH);
    double a0 = 0.0, a1 = 0.0, a2 = 0.0, a3 = 0.0;
#pragma unroll
    for (int u = 0; u < 16; ++u) {
      a0 += (double)v[u].x; a1 += (double)v[u].y;
      a2 += (double)v[u].z; a3 += (double)v[u].w;
    }
    double* o = qpart + (size_t)(qb * 2 + rh) * HH + fg * 4;
    o[0] = a0; o[1] = a1; o[2] = a2; o[3] = a3;
    return;
  }

  // ---- proj (ids [0,256)): A = W frags, B = gathered clause (otf split) ----
  const int pid = id;
  const int rowt = pid & 31, colt = (pid >> 5) & 3, z = pid >> 7;
  const int* __restrict__ idx = z ? neg_idx : pos_idx;
  const u16* __restrict__ whp = z ? pwkhi : pwqhi;
  const u16* __restrict__ wlp = z ? pwklo : pwqlo;
  const float* __restrict__ bias = z ? bK : bQ;
  u16* __restrict__ ohi = z ? khi : qhi;
  u16* __restrict__ olo = z ? klo : qlo;

  const int wn = wid & 1, wm = wid >> 1;
  const int row0 = rowt * 128;
  const int col0 = colt * 128;

  const float* bptr[4];
#pragma unroll
  for (int j = 0; j < 4; ++j) {
    int g = idx[row0 + wn * 64 + j * 16 + (lane & 15)];
    bptr[j] = clause + (size_t)g * HH + (lane >> 4) * 8;
  }
  const size_t abase = (size_t)((col0 >> 4) + wm * 4) * 8192 + (size_t)lane * 8;

  f32x4 acc[4][4] = {};
#pragma unroll
  for (int s = 0; s < 16; ++s) {
    float rB[4][8];
    bf16x8 aH[4], aL[4], bH[4], bL[4];
#pragma unroll
    for (int f = 0; f < 4; ++f) {
      *(float4*)&rB[f][0] = *(const float4*)(bptr[f] + s * 32);
      *(float4*)&rB[f][4] = *(const float4*)(bptr[f] + s * 32 + 4);
      size_t oa = abase + (size_t)f * 8192 + (size_t)s * 512;
      aH[f] = *(const bf16x8*)(whp + oa);
      aL[f] = *(const bf16x8*)(wlp + oa);
    }
#pragma unroll
    for (int f = 0; f < 4; ++f)
#pragma unroll
      for (int e = 0; e < 8; ++e) {
        float v = rB[f][e];
        u16 h = f2bf(v);
        bH[f][e] = (short)h;
        bL[f][e] = (short)f2bf(v - bf2f(h));
      }
    MFMA16(aH, bH)
    MFMA16(aL, bH)
    MFMA16(aH, bL)
  }

  const int q4 = lane >> 4;
#pragma unroll
  for (int i = 0; i < 4; ++i) {
    const int hbase = col0 + wm * 64 + i * 16 + q4 * 4;
    float b0 = bias[hbase + 0], b1 = bias[hbase + 1];
    float b2 = bias[hbase + 2], b3 = bias[hbase + 3];
    const int lane16 = (lane & 15) + ((i & 1) * 2 + (q4 >> 1)) * 16;
    const int sub = (q4 & 1) * 4;
#pragma unroll
    for (int j = 0; j < 4; ++j) {
      const int frag = ((row0 + wn * 64 + j * 16) >> 4) * 16 +
                       ((col0 + wm * 64 + i * 16) >> 5);
      size_t base = (size_t)frag * 512 + (size_t)lane16 * 8 + sub;
      ushort4 hv, lv;
      float v;
      v = acc[i][j][0] + b0; hv.x = f2bf(v); lv.x = f2bf(v - bf2f(hv.x));
      v = acc[i][j][1] + b1; hv.y = f2bf(v); lv.y = f2bf(v - bf2f(hv.y));
      v = acc[i][j][2] + b2; hv.z = f2bf(v); lv.z = f2bf(v - bf2f(hv.z));
      v = acc[i][j][3] + b3; hv.w = f2bf(v); lv.w = f2bf(v - bf2f(hv.w));
      *(ushort4*)(ohi + base) = hv;
      *(ushort4*)(olo + base) = lv;
    }
  }
}

// reduce 4096 partial Q vectors -> Qd[512] (f64), batched loads
__global__ __launch_bounds__(256) void qred_kernel(
    const double* __restrict__ qpart, double* __restrict__ Qd) {
  __shared__ double red[256];
  const int t = threadIdx.x;
  const int h = blockIdx.x * 16 + (t & 15);
  const int chunk = t >> 4;
  double s = 0.0;
  for (int j0 = 0; j0 < 256; j0 += 8) {
    double v[8];
#pragma unroll
    for (int u = 0; u < 8; ++u)
      v[u] = qpart[(size_t)(chunk * 256 + j0 + u) * HH + h];
#pragma unroll
    for (int u = 0; u < 8; ++u) s += v[u];
  }
  red[t] = s;
  __syncthreads();
  for (int off = 8; off > 0; off >>= 1) {
    if (chunk < off) red[t] += red[t + off * 16];
    __syncthreads();
  }
  if (t < 16) Qd[blockIdx.x * 16 + t] = red[t];
}

// tvec[h] = (Q @ var_Q_w.T)[h] + var_Q_b[h] + var_K_b[h]
__global__ __launch_bounds__(256) void prepmv_kernel(
    const double* __restrict__ Qd, const float* __restrict__ varQw,
    const float* __restrict__ varQb, const float* __restrict__ varKb,
    float* __restrict__ tvec) {
  __shared__ double red[256];
  const int t = threadIdx.x;
  const int h = blockIdx.x * 16 + (t & 15);
  const int chunk = t >> 4;
  const float* wrow = varQw + (size_t)h * HH + chunk * 32;
  const double* qd = Qd + chunk * 32;
  double s = 0.0;
  for (int j = 0; j < 32; ++j) s += qd[j] * (double)wrow[j];
  red[t] = s;
  __syncthreads();
  for (int off = 8; off > 0; off >>= 1) {
    if (chunk < off) red[t] += red[t + off * 16];
    __syncthreads();
  }
  if (t < 16) {
    int hh = blockIdx.x * 16 + t;
    tvec[hh] = (float)(red[t] + (double)varQb[hh] + (double)varKb[hh]);
  }
}

// ---------------------------------------------------------------------------
// scores: LDS-staged 3-pass split MFMA + XCD supertile swizzle, with INLINE
// mask build from keep/taken (grid tiles the mask exactly once — pack
// absorbed, mask stream hides under MFMA).
__global__ __launch_bounds__(256, 2) void scores_kernel(
    const u16* __restrict__ qhi, const u16* __restrict__ qlo,
    const u16* __restrict__ khi, const u16* __restrict__ klo,
    const void* __restrict__ keep, const void* __restrict__ taken,
    SPart* __restrict__ parts) {
  __shared__ __align__(16) u16 lds[2][4][8][512];
  __shared__ unsigned long long mrow[128][2];
  __shared__ float s_rv[4]; __shared__ int s_ri[4]; __shared__ float s_rs[4];
  __shared__ float s_bm; __shared__ int s_ba;

  const int t = threadIdx.x;
  const int lane = t & 63;
  const int wid = t >> 6;
  const int wn = wid & 1, wm = wid >> 1;
  const int l8 = lane * 8;

  // XCD supertile swizzle (bijective on [0,1024))
  const int bid = blockIdx.x;
  const int xcd = bid & 7, p = bid >> 3;
  const int sp = p >> 6, q = p & 63;
  const int g = xcd * 2 + sp;
  const int bx = (g & 3) * 8 + (q & 7);
  const int by = (g >> 2) * 8 + (q >> 3);

  const int n0 = by * 128;
  const int m0 = bx * 128;

  const u16* sa = (wid == 0) ? qhi : (wid == 1) ? qlo : (wid == 2) ? khi : klo;
  const int rb = (wid < 2) ? (n0 >> 4) : (m0 >> 4);
  const u16* sab = sa + (size_t)rb * 8192 + l8;

#define SSTAGE(buf, s)                                                        \
  _Pragma("unroll") for (int f_ = 0; f_ < 8; ++f_)                            \
    stage_frag(sab + (size_t)f_ * 8192 + (size_t)(s) * 512,                   \
               &lds[buf][wid][f_][0]);

  SSTAGE(0, 0)

  // inline mask build: thread t covers row t>>1, col-half t&1
  {
    const int r = t >> 1, half = t & 1;
    const unsigned* kw = (const unsigned*)keep;
    int f = 1;
#pragma unroll
    for (int i = 0; i < 16; ++i) f &= (kw[i] <= 1u);
    unsigned long long w = 0;
    if (!f) {
      const u8* kp = (const u8*)keep + (size_t)(n0 + r) * NMS + m0 + half * 64;
      const u8* tp = (const u8*)taken + (size_t)(n0 + r) * NMS + m0 + half * 64;
#pragma unroll
      for (int c = 0; c < 4; ++c) {
        uint4 kv = *(const uint4*)(kp + c * 16);
        uint4 tv = *(const uint4*)(tp + c * 16);
        unsigned kws[4] = {kv.x, kv.y, kv.z, kv.w};
        unsigned tws[4] = {tv.x, tv.y, tv.z, tv.w};
#pragma unroll
        for (int wi = 0; wi < 4; ++wi)
#pragma unroll
          for (int y = 0; y < 4; ++y) {
            unsigned kb = (kws[wi] >> (8 * y)) & 0xffu;
            unsigned tb = (tws[wi] >> (8 * y)) & 0xffu;
            w |= (unsigned long long)(kb && !tb) << (c * 16 + wi * 4 + y);
          }
      }
    } else {
      const unsigned* kp = (const unsigned*)keep + (size_t)(n0 + r) * NMS + m0 + half * 64;
      const unsigned* tp = (const unsigned*)taken + (size_t)(n0 + r) * NMS + m0 + half * 64;
#pragma unroll
      for (int c = 0; c < 16; ++c) {
        uint4 kv = *(const uint4*)(kp + c * 4);
        uint4 tv = *(const uint4*)(tp + c * 4);
        w |= (unsigned long long)(kv.x && !tv.x) << (c * 4 + 0);
        w |= (unsigned long long)(kv.y && !tv.y) << (c * 4 + 1);
        w |= (unsigned long long)(kv.z && !tv.z) << (c * 4 + 2);
        w |= (unsigned long long)(kv.w && !tv.w) << (c * 4 + 3);
      }
    }
    mrow[r][half] = w;
  }

  f32x4 acc[4][4] = {};
#pragma unroll
  for (int s = 0; s < 16; ++s) {
    __syncthreads();
    if (s < 15) { SSTAGE((s + 1) & 1, s + 1) }
    const int b = s & 1;
    bf16x8 aH[4], aL[4], bH[4], bL[4];
#pragma unroll
    for (int f = 0; f < 4; ++f) {
      aH[f] = *(const bf16x8*)&lds[b][0][wn * 4 + f][l8];
      aL[f] = *(const bf16x8*)&lds[b][1][wn * 4 + f][l8];
      bH[f] = *(const bf16x8*)&lds[b][2][wm * 4 + f][l8];
      bL[f] = *(const bf16x8*)&lds[b][3][wm * 4 + f][l8];
    }
    MFMAS(aH, aL, bH, bL);
  }
#undef SSTAGE

  // C/D layout: col = lane&15, row = (lane>>4)*4 + reg
  const int rbase = wn * 64 + (lane >> 4) * 4;
  const int cb15 = (lane & 15);

  float mv = NEGV; int mi = 0x7fffffff;
#pragma unroll
  for (int i = 0; i < 4; ++i) {
#pragma unroll
    for (int r = 0; r < 4; ++r) {
      int rl = rbase + i * 16 + r;
      unsigned long long ww = mrow[rl][wm];
      int gb = (n0 + rl) * NMS + m0;
#pragma unroll
      for (int j = 0; j < 4; ++j) {
        int bit = j * 16 + cb15;
        int cl = wm * 64 + bit;
        float sv = acc[i][j][r] * RSQRT_H;
        acc[i][j][r] = sv;
        bool valid = ((ww >> bit) & 1ull) != 0;
        if (valid && (sv > mv || (sv == mv && gb + cl < mi))) { mv = sv; mi = gb + cl; }
      }
    }
  }
  wreduce_maxidx(mv, mi);
  if ((t & 63) == 0) { s_rv[wid] = mv; s_ri[wid] = mi; }
  __syncthreads();
  if (t == 0) {
    float bm = s_rv[0]; int ba = s_ri[0];
    for (int w = 1; w < 4; ++w)
      if (s_rv[w] > bm || (s_rv[w] == bm && s_ri[w] < ba)) { bm = s_rv[w]; ba = s_ri[w]; }
    s_bm = bm; s_ba = ba;
  }
  __syncthreads();
  const float bm = s_bm;

  float se = 0.f;
#pragma unroll
  for (int i = 0; i < 4; ++i) {
#pragma unroll
    for (int r = 0; r < 4; ++r) {
      int rl = rbase + i * 16 + r;
      unsigned long long ww = mrow[rl][wm];
#pragma unroll
      for (int j = 0; j < 4; ++j) {
        int bit = j * 16 + cb15;
        bool valid = ((ww >> bit) & 1ull) != 0;
        if (valid) se += __expf(acc[i][j][r] - bm);
      }
    }
  }
  se = wreduce_sum(se);
  if ((t & 63) == 0) s_rs[wid] = se;
  __syncthreads();
  if (t == 0) {
    SPart pt;
    pt.m = s_bm;
    pt.s = s_rs[0] + s_rs[1] + s_rs[2] + s_rs[3];
    pt.a = s_ba; pt.pad = 0;
    parts[by * 32 + bx] = pt;
  }
}

// ---------------------------------------------------------------------------
// K_t GEMM (lit @ varKw.T) via LDS-staged MFMA on pre-split frags; tanh epi.
__global__ __launch_bounds__(256, 2) void ktu_kernel(
    const u16* __restrict__ lithi, const u16* __restrict__ litlo,
    const u16* __restrict__ wkhi, const u16* __restrict__ wklo,
    const float* __restrict__ tvec, const float* __restrict__ attnw,
    float* __restrict__ upart) {
  __shared__ __align__(16) u16 lds[2][4][8][512];
  const int t = threadIdx.x, lane = t & 63, wid = t >> 6;
  const int wn = wid & 1, wm = wid >> 1;
  const int row0 = blockIdx.x * 128;
  const int l8 = lane * 8;

  const u16* sa = (wid == 0) ? lithi : (wid == 1) ? litlo : (wid == 2) ? wkhi : wklo;
  const int rb = (wid < 2) ? (row0 >> 4) : (blockIdx.y * 8);
  const u16* sab = sa + (size_t)rb * 8192 + l8;

#define KSTAGE(buf, s)                                                        \
  _Pragma("unroll") for (int f_ = 0; f_ < 8; ++f_)                            \
    stage_frag(sab + (size_t)f_ * 8192 + (size_t)(s) * 512,                   \
               &lds[buf][wid][f_][0]);

  KSTAGE(0, 0)
  f32x4 acc[4][4] = {};
#pragma unroll
  for (int s = 0; s < 16; ++s) {
    __syncthreads();
    if (s < 15) { KSTAGE((s + 1) & 1, s + 1) }
    const int b = s & 1;
    bf16x8 aH[4], aL[4], bH[4], bL[4];
#pragma unroll
    for (int f = 0; f < 4; ++f) {
      aH[f] = *(const bf16x8*)&lds[b][0][wn * 4 + f][l8];
      aL[f] = *(const bf16x8*)&lds[b][1][wn * 4 + f][l8];
      bH[f] = *(const bf16x8*)&lds[b][2][wm * 4 + f][l8];
      bL[f] = *(const bf16x8*)&lds[b][3][wm * 4 + f][l8];
    }
    MFMAS(aH, aL, bH, bL);
  }
#undef KSTAGE

  const int cbase = blockIdx.y * 128 + wm * 64;
  float tv[4], aw[4];
#pragma unroll
  for (int j = 0; j < 4; ++j) {
    int c = cbase + j * 16 + (lane & 15);
    tv[j] = tvec[c]; aw[j] = attnw[c];
  }
  float us[4][4];
#pragma unroll
  for (int i = 0; i < 4; ++i)
#pragma unroll
    for (int r = 0; r < 4; ++r) {
      float s = 0.f;
#pragma unroll
      for (int j = 0; j < 4; ++j) {
        float x = acc[i][j][r] + tv[j];
        float th = 1.0f - 2.0f / (__expf(2.0f * x) + 1.0f);   // safe tanh
        s += th * aw[j];
      }
      us[i][r] = s;
    }
#pragma unroll
  for (int m = 1; m < 16; m <<= 1)
#pragma unroll
    for (int i = 0; i < 4; ++i)
#pragma unroll
      for (int r = 0; r < 4; ++r) us[i][r] += __shfl_xor(us[i][r], m, 64);
  if ((lane & 15) == 0) {
#pragma unroll
    for (int i = 0; i < 4; ++i)
#pragma unroll
      for (int r = 0; r < 4; ++r) {
        int row = row0 + wn * 64 + i * 16 + (lane >> 4) * 4 + r;
        upart[(size_t)(blockIdx.y * 2 + wm) * NVARS + row] = us[i][r];
      }
  }
}

// ---------------------------------------------------------------------------
// u reduction stage 1: 64 blocks x 256 vars -> per-block {max, argmax, sumexp}.
__global__ __launch_bounds__(256) void usum_kernel(
    const float* __restrict__ upart, SPart* __restrict__ uparts2) {
  __shared__ float s_rv[4]; __shared__ int s_ri[4]; __shared__ float s_rs[4];
  __shared__ float s_bm; __shared__ int s_ba;
  const int t = threadIdx.x;
  const int i = blockIdx.x * 256 + t;
  float u = 0.f;
#pragma unroll
  for (int p = 0; p < 8; ++p) u += upart[(size_t)p * NVARS + i];
  float mv = u; int mi = i;
  wreduce_maxidx(mv, mi);
  if ((t & 63) == 0) { s_rv[t >> 6] = mv; s_ri[t >> 6] = mi; }
  __syncthreads();
  if (t == 0) {
    float bm = s_rv[0]; int ba = s_ri[0];
    for (int w = 1; w < 4; ++w)
      if (s_rv[w] > bm || (s_rv[w] == bm && s_ri[w] < ba)) { bm = s_rv[w]; ba = s_ri[w]; }
    s_bm = bm; s_ba = ba;
  }
  __syncthreads();
  float se = __expf(u - s_bm);
  se = wreduce_sum(se);
  if ((t & 63) == 0) s_rs[t >> 6] = se;
  __syncthreads();
  if (t == 0) {
    SPart p;
    p.m = s_bm;
    p.s = s_rs[0] + s_rs[1] + s_rs[2] + s_rs[3];
    p.a = s_ba; p.pad = 0;
    uparts2[blockIdx.x] = p;
  }
}

// ---------------------------------------------------------------------------
// Final combine.  d_out is FLOAT32 x4: {c_logp, pos_idx[ci], neg_idx[cj], var_idx}.
__global__ __launch_bounds__(256) void final_kernel(
    const SPart* __restrict__ uparts2, const SPart* __restrict__ parts,
    const int* __restrict__ pos_idx, const int* __restrict__ neg_idx,
    float* __restrict__ out) {
  __shared__ float s_rv[4]; __shared__ int s_ri[4]; __shared__ float s_rs[4];
  __shared__ float s_umax; __shared__ int s_uarg; __shared__ float s_usum;
  __shared__ float s_gm; __shared__ int s_ga;
  const int t = threadIdx.x;

  float mv = -3.0e38f; int mi = 0x7fffffff;
  SPart up;
  if (t < 64) {
    up = uparts2[t];
    mv = up.m; mi = up.a;
  }
  wreduce_maxidx(mv, mi);
  if ((t & 63) == 0) { s_rv[t >> 6] = mv; s_ri[t >> 6] = mi; }
  __syncthreads();
  if (t == 0) {
    float bm = s_rv[0]; int ba = s_ri[0];
    for (int w = 1; w < 4; ++w)
      if (s_rv[w] > bm || (s_rv[w] == bm && s_ri[w] < ba)) { bm = s_rv[w]; ba = s_ri[w]; }
    s_umax = bm; s_uarg = ba;
  }
  __syncthreads();
  float se = (t < 64) ? up.s * __expf(up.m - s_umax) : 0.f;
  se = wreduce_sum(se);
  if ((t & 63) == 0) s_rs[t >> 6] = se;
  __syncthreads();
  if (t == 0) s_usum = s_rs[0] + s_rs[1] + s_rs[2] + s_rs[3];
  __syncthreads();

  mv = NEGV; mi = 0x7fffffff;
  for (int i = t; i < 1024; i += 256) {
    SPart p = parts[i];
    if (p.m > mv || (p.m == mv && p.a < mi)) { mv = p.m; mi = p.a; }
  }
  wreduce_maxidx(mv, mi);
  if ((t & 63) == 0) { s_rv[t >> 6] = mv; s_ri[t >> 6] = mi; }
  __syncthreads();
  if (t == 0) {
    float bm = s_rv[0]; int ba = s_ri[0];
    for (int w = 1; w < 4; ++w)
      if (s_rv[w] > bm || (s_rv[w] == bm && s_ri[w] < ba)) { bm = s_rv[w]; ba = s_ri[w]; }
    s_gm = bm; s_ga = ba;
  }
  __syncthreads();
  const float gm = s_gm;
  float ss = 0.f;
  for (int i = t; i < 1024; i += 256) {
    SPart p = parts[i];
    ss += p.s * __expf(p.m - gm);
  }
  ss = wreduce_sum(ss);
  if ((t & 63) == 0) s_rs[t >> 6] = ss;
  __syncthreads();
  if (t == 0) {
    float gsum = s_rs[0] + s_rs[1] + s_rs[2] + s_rs[3];
    float c_logp = -logf(gsum) - logf(s_usum);
    int ga = s_ga;
    if (ga == 0x7fffffff) ga = 0;
    int ci = ga >> 12, cj = ga & 4095;
    out[0] = c_logp;
    out[1] = (float)pos_idx[ci];
    out[2] = (float)neg_idx[cj];
    out[3] = (float)s_uarg;
  }
}

extern "C" void kernel_launch(void* const* d_in, const int* in_sizes, int n_in,
                              void* d_out, int out_size, void* d_ws, size_t ws_size,
                              hipStream_t stream) {
  (void)in_sizes; (void)n_in; (void)out_size; (void)ws_size;
  const float* lit    = (const float*)d_in[0];
  const float* clause = (const float*)d_in[1];
  const int* pos_idx  = (const int*)d_in[2];
  const int* neg_idx  = (const int*)d_in[3];
  const void* keep    = d_in[4];
  const void* taken   = d_in[5];
  const float* varKw  = (const float*)d_in[6];
  const float* varKb  = (const float*)d_in[7];
  const float* varQw  = (const float*)d_in[8];
  const float* varQb  = (const float*)d_in[9];
  const float* attnw  = (const float*)d_in[10];
  // d_in[11] var_attn_b: uniform shift, cancels in log_softmax max/argmax
  const float* WQw    = (const float*)d_in[12];
  const float* WQb    = (const float*)d_in[13];
  const float* WKw    = (const float*)d_in[14];
  const float* WKb    = (const float*)d_in[15];

  char* ws = (char*)d_ws;
  size_t off = 0;
  auto alloc = [&](size_t b) {
    char* p = ws + off;
    off = (off + b + 255) & ~(size_t)255;
    return p;
  };
  double* qpart              = (double*)alloc((size_t)4096 * HH * 8);
  double* Qd                 = (double*)alloc(HH * 8);
  float* tvec                = (float*)alloc(HH * 4);
  float* upart               = (float*)alloc(8 * (size_t)NVARS * 4);
  u16* qhi                   = (u16*)alloc((size_t)NPOS * HH * 2);
  u16* qlo                   = (u16*)alloc((size_t)NPOS * HH * 2);
  u16* khi                   = (u16*)alloc((size_t)NMS * HH * 2);
  u16* klo                   = (u16*)alloc((size_t)NMS * HH * 2);
  u16* wkhi                  = (u16*)alloc((size_t)HH * HH * 2);
  u16* wklo                  = (u16*)alloc((size_t)HH * HH * 2);
  u16* pwqhi                 = (u16*)alloc((size_t)HH * HH * 2);
  u16* pwqlo                 = (u16*)alloc((size_t)HH * HH * 2);
  u16* pwkhi                 = (u16*)alloc((size_t)HH * HH * 2);
  u16* pwklo                 = (u16*)alloc((size_t)HH * HH * 2);
  u16* lithi                 = (u16*)alloc((size_t)NVARS * HH * 2);
  u16* litlo                 = (u16*)alloc((size_t)NVARS * HH * 2);
  SPart* parts               = (SPart*)alloc(1024 * sizeof(SPart));
  SPart* uparts2             = (SPart*)alloc(64 * sizeof(SPart));

  wtofrag_kernel<<<384, 256, 0, stream>>>(varKw, wkhi, wklo,
                                          WQw, pwqhi, pwqlo,
                                          WKw, pwkhi, pwklo);
  megaA_kernel<<<6400, 256, 0, stream>>>(clause, pos_idx, neg_idx,
                                         pwqhi, pwqlo, pwkhi, pwklo,
                                         WQb, WKb, qhi, qlo, khi, klo,
                                         qpart, lit, lithi, litlo);
  qred_kernel<<<32, 256, 0, stream>>>(qpart, Qd);
  prepmv_kernel<<<32, 256, 0, stream>>>(Qd, varQw, varQb, varKb, tvec);
  scores_kernel<<<1024, 256, 0, stream>>>(qhi, qlo, khi, klo, keep, taken, parts);
  ktu_kernel<<<dim3(128, 4), 256, 0, stream>>>(lithi, litlo, wkhi, wklo,
                                               tvec, attnw, upart);
  usum_kernel<<<64, 256, 0, stream>>>(upart, uparts2);
  final_kernel<<<1, 256, 0, stream>>>(uparts2, parts, pos_idx, neg_idx,
                                      (float*)d_out);
}